// Round 13
// baseline (745.744 us; speedup 1.0000x reference)
//
#include <hip/hip_runtime.h>

// Round 13: fp16 precision scheme on the proven R9 structure (mask back in
// softmax -- R11/R12 fusions both lost to it).
//  - proj: 3-term fp16 (queryh,queryl)x(Wh,Wl) -> q as fp16 hi/lo   [safe]
//  - QK:   2-term fp16 (qh+ql) x memh  -- mem-lo dropped: logit noise ~7e-3,
//          B-tile halves -> LDS 24KB -> more blocks/CU
//  - PV:   1-term fp16 P x memT (errors shrink 4x vs bf16)
// MFMA work: QK 206->137 GF. Same kernel skeleton, XOR involutions, epilogue.

typedef __attribute__((ext_vector_type(8))) _Float16 f16x8;
typedef __attribute__((ext_vector_type(4))) float f32x4;
typedef unsigned short u16;
typedef unsigned int u32;

#define B_ 8
#define SQL 2048
#define SKL 2048
#define DD 1024
#define NEGC -1000000000.0f

static __device__ __forceinline__ u16 f2h(float x) {
  _Float16 h = (_Float16)x;                       // v_cvt_f16_f32, RNE
  return __builtin_bit_cast(u16, h);
}
static __device__ __forceinline__ float h2f(u16 v) {
  return (float)__builtin_bit_cast(_Float16, v);
}
static __device__ __forceinline__ void gload16(const void* g, void* l) {
  __builtin_amdgcn_global_load_lds((const __attribute__((address_space(1))) u32*)g,
                                   (__attribute__((address_space(3))) u32*)l, 16, 0, 0);
}

// ---------------- split fp32 -> fp16 hi + fp16 lo ----------------
__global__ __launch_bounds__(256) void split16_k(const float* __restrict__ in,
                                                 u16* __restrict__ hi, u16* __restrict__ lo,
                                                 long n) {
  long i = ((long)blockIdx.x * 256 + threadIdx.x) * 4;
  long stride = (long)gridDim.x * 256 * 4;
  for (; i < n; i += stride) {
    float4 v = *(const float4*)(in + i);
    u16 h0 = f2h(v.x), h1 = f2h(v.y), h2 = f2h(v.z), h3 = f2h(v.w);
    *(ushort4*)(hi + i) = make_ushort4(h0, h1, h2, h3);
    *(ushort4*)(lo + i) = make_ushort4(f2h(v.x - h2f(h0)), f2h(v.y - h2f(h1)),
                                       f2h(v.z - h2f(h2)), f2h(v.w - h2f(h3)));
  }
}

// ---------------- fused mem: fp32 [Sk][D] -> memh fp16 + memT fp16 [D][Sk] ----------------
__global__ __launch_bounds__(256) void split_mem16_k(const float* __restrict__ in,
                                                     u16* __restrict__ hi,
                                                     u16* __restrict__ trn) {
  __shared__ u16 t[64][65];
  long bo = (long)blockIdx.z * SKL * DD;
  int r0 = blockIdx.y * 64, c0 = blockIdx.x * 64;
  int tr = threadIdx.x / 16, tc4 = (threadIdx.x % 16) * 4;
#pragma unroll
  for (int i = 0; i < 4; ++i) {
    int r = tr + i * 16;
    long idx = bo + (long)(r0 + r) * DD + c0 + tc4;
    float4 v = *(const float4*)(in + idx);
    u16 h0 = f2h(v.x), h1 = f2h(v.y), h2 = f2h(v.z), h3 = f2h(v.w);
    *(ushort4*)(hi + idx) = make_ushort4(h0, h1, h2, h3);
    t[r][tc4 + 0] = h0; t[r][tc4 + 1] = h1; t[r][tc4 + 2] = h2; t[r][tc4 + 3] = h3;
  }
  __syncthreads();
#pragma unroll
  for (int i = 0; i < 4; ++i) {
    int c = tr + i * 16;   // output row = original column c0+c
    ushort4 v = make_ushort4(t[tc4 + 0][c], t[tc4 + 1][c], t[tc4 + 2][c], t[tc4 + 3][c]);
    *(ushort4*)(trn + bo + (long)(c0 + c) * SKL + r0 + tc4) = v;
  }
}

// ---------------- unified B^T-layout fp16 MFMA GEMM ----------------
// C[m][n] = sum_k A[m][k]*B[n][k]; 128x128 tile, 4 waves (2x2),
// mfma_f32_16x16x32_f16, single-buffer LDS (R9 structure), XOR-swizzled via
// pre-swizzled global source.
// TERMS=3: BK=32, A,B rows 64 u16 (hi 0-3 | lo 4-7).   proj
// TERMS=2: BK=32, A rows 64 u16 (hi|lo), B rows 32 u16 (hi, 4 chunks). QK
// TERMS=1: BK=64, A,B rows 64 u16 (single dtype, 8 chunks).          PV
// OUTMODE: 0 = fp32 ; 2 = fp16 hi + lo (to C0,C1)
template <int TERMS, int OUTMODE, bool BIAS>
__global__ __launch_bounds__(256, 4) void gemm_f16(
    const u16* __restrict__ Ah, const u16* __restrict__ Al,
    const u16* __restrict__ Bh, const u16* __restrict__ Bl,
    const float* __restrict__ bias,
    void* __restrict__ C0, void* __restrict__ C1,
    int N, int K, long batchA, long batchB, long batchC) {
  constexpr int KSTEP = (TERMS >= 2) ? 32 : 64;
  constexpr int RWB = (TERMS == 2) ? 32 : 64;   // u16 per B LDS row
  __shared__ u16 lA[128 * 64];
  __shared__ u16 lB[128 * RWB];

  const int bz = blockIdx.z;
  const u16* pAh = Ah + (long)bz * batchA;
  const u16* pBh = Bh + (long)bz * batchB;
  const u16* pAl = (TERMS >= 2) ? (Al + (long)bz * batchA) : nullptr;
  const u16* pBl = (TERMS == 3) ? (Bl + (long)bz * batchB) : nullptr;

  const int tid = threadIdx.x;
  const int l = tid & 63, w = tid >> 6;
  const int wr = w >> 1, wc = w & 1;
  const long am0 = (long)blockIdx.y * 128;
  const long bn0 = (long)blockIdx.x * 128;

  f32x4 acc[4][4];
#pragma unroll
  for (int i = 0; i < 4; ++i)
#pragma unroll
    for (int j = 0; j < 4; ++j) {
      f32x4 z = {0.f, 0.f, 0.f, 0.f};
      acc[i][j] = z;
    }

  const int lrow = l & 15, lch = l >> 4;

  for (int k0 = 0; k0 < K; k0 += KSTEP) {
    __syncthreads();
    // ---- A stage: 8 chunks/row, proven involution ----
#pragma unroll
    for (int i = 0; i < 4; ++i) {
      int row = i * 32 + (tid >> 3);
      int cc = (tid & 7) ^ (row & 7);
      const u16* sA;
      if (TERMS >= 2)
        sA = (cc >= 4) ? (pAl + (am0 + row) * K + k0 + (cc - 4) * 8)
                       : (pAh + (am0 + row) * K + k0 + cc * 8);
      else
        sA = pAh + (am0 + row) * K + k0 + cc * 8;
      gload16(sA, &lA[row * 64 + (tid & 7) * 8]);
    }
    // ---- B stage ----
    if (TERMS == 2) {
#pragma unroll
      for (int i = 0; i < 2; ++i) {
        int row = i * 64 + (tid >> 2);
        int cc = (tid & 3) ^ (row & 3);   // 4-chunk involution
        gload16(pBh + (bn0 + row) * K + k0 + cc * 8, &lB[row * 32 + (tid & 3) * 8]);
      }
    } else {
#pragma unroll
      for (int i = 0; i < 4; ++i) {
        int row = i * 32 + (tid >> 3);
        int cc = (tid & 7) ^ (row & 7);
        const u16* sB;
        if (TERMS == 3)
          sB = (cc >= 4) ? (pBl + (bn0 + row) * K + k0 + (cc - 4) * 8)
                         : (pBh + (bn0 + row) * K + k0 + cc * 8);
        else
          sB = pBh + (bn0 + row) * K + k0 + cc * 8;
        gload16(sB, &lB[row * 64 + (tid & 7) * 8]);
      }
    }
    __syncthreads();

    if (TERMS == 3) {
      f16x8 ah[4], bh[4], al_[4], bl_[4];
#pragma unroll
      for (int f = 0; f < 4; ++f) {
        int ra = wr * 64 + f * 16 + lrow;
        int rb = wc * 64 + f * 16 + lrow;
        ah[f] = *(const f16x8*)&lA[ra * 64 + (lch ^ (ra & 7)) * 8];
        bh[f] = *(const f16x8*)&lB[rb * 64 + (lch ^ (rb & 7)) * 8];
        al_[f] = *(const f16x8*)&lA[ra * 64 + ((4 + lch) ^ (ra & 7)) * 8];
        bl_[f] = *(const f16x8*)&lB[rb * 64 + ((4 + lch) ^ (rb & 7)) * 8];
      }
#pragma unroll
      for (int mf = 0; mf < 4; ++mf)
#pragma unroll
        for (int nf = 0; nf < 4; ++nf) {
          acc[mf][nf] = __builtin_amdgcn_mfma_f32_16x16x32_f16(ah[mf], bh[nf], acc[mf][nf], 0, 0, 0);
          acc[mf][nf] = __builtin_amdgcn_mfma_f32_16x16x32_f16(ah[mf], bl_[nf], acc[mf][nf], 0, 0, 0);
          acc[mf][nf] = __builtin_amdgcn_mfma_f32_16x16x32_f16(al_[mf], bh[nf], acc[mf][nf], 0, 0, 0);
        }
    } else if (TERMS == 2) {
      f16x8 ah[4], al_[4], bh[4];
#pragma unroll
      for (int f = 0; f < 4; ++f) {
        int ra = wr * 64 + f * 16 + lrow;
        int rb = wc * 64 + f * 16 + lrow;
        ah[f] = *(const f16x8*)&lA[ra * 64 + (lch ^ (ra & 7)) * 8];
        al_[f] = *(const f16x8*)&lA[ra * 64 + ((4 + lch) ^ (ra & 7)) * 8];
        bh[f] = *(const f16x8*)&lB[rb * 32 + (lch ^ (rb & 3)) * 8];
      }
#pragma unroll
      for (int mf = 0; mf < 4; ++mf)
#pragma unroll
        for (int nf = 0; nf < 4; ++nf) {
          acc[mf][nf] = __builtin_amdgcn_mfma_f32_16x16x32_f16(ah[mf], bh[nf], acc[mf][nf], 0, 0, 0);
          acc[mf][nf] = __builtin_amdgcn_mfma_f32_16x16x32_f16(al_[mf], bh[nf], acc[mf][nf], 0, 0, 0);
        }
    } else {
#pragma unroll
      for (int kk = 0; kk < 2; ++kk) {
        f16x8 ah[4], bh[4];
#pragma unroll
        for (int f = 0; f < 4; ++f) {
          int ra = wr * 64 + f * 16 + lrow;
          int rb = wc * 64 + f * 16 + lrow;
          int c = kk * 4 + lch;
          ah[f] = *(const f16x8*)&lA[ra * 64 + (c ^ (ra & 7)) * 8];
          bh[f] = *(const f16x8*)&lB[rb * 64 + (c ^ (rb & 7)) * 8];
        }
#pragma unroll
        for (int mf = 0; mf < 4; ++mf)
#pragma unroll
          for (int nf = 0; nf < 4; ++nf)
            acc[mf][nf] = __builtin_amdgcn_mfma_f32_16x16x32_f16(ah[mf], bh[nf], acc[mf][nf], 0, 0, 0);
      }
    }
  }

  // epilogue: C/D layout col = lane&15, row = (lane>>4)*4 + reg
#pragma unroll
  for (int mf = 0; mf < 4; ++mf)
#pragma unroll
    for (int nf = 0; nf < 4; ++nf)
#pragma unroll
      for (int r = 0; r < 4; ++r) {
        long row = am0 + wr * 64 + mf * 16 + (l >> 4) * 4 + r;
        long col = bn0 + wc * 64 + nf * 16 + (l & 15);
        float v = acc[mf][nf][r];
        if (BIAS) v += bias[col];
        long idx = (long)bz * batchC + row * N + col;
        if (OUTMODE == 0) {
          ((float*)C0)[idx] = v;
        } else {
          u16 h = f2h(v);
          ((u16*)C0)[idx] = h;
          ((u16*)C1)[idx] = f2h(v - h2f(h));
        }
      }
}

// ---------------- mask + row softmax: S fp32, mask int32 -> P fp16 ----------------
__global__ __launch_bounds__(256) void softmax16_k(const float* __restrict__ S,
                                                   const int* __restrict__ M,
                                                   u16* __restrict__ P) {
  long row = blockIdx.x;
  const float* s = S + row * SKL;
  const int* m = M + row * SKL;
  u16* p = P + row * SKL;
  int t = threadIdx.x;
  float x[8];
#pragma unroll
  for (int j = 0; j < 2; ++j) {
    float4 v = *(const float4*)(s + t * 8 + j * 4);
    int4 q = *(const int4*)(m + t * 8 + j * 4);
    x[j * 4 + 0] = q.x ? v.x : v.x + NEGC;
    x[j * 4 + 1] = q.y ? v.y : v.y + NEGC;
    x[j * 4 + 2] = q.z ? v.z : v.z + NEGC;
    x[j * 4 + 3] = q.w ? v.w : v.w + NEGC;
  }
  float mx = x[0];
#pragma unroll
  for (int j = 1; j < 8; ++j) mx = fmaxf(mx, x[j]);
#pragma unroll
  for (int o = 32; o >= 1; o >>= 1) mx = fmaxf(mx, __shfl_xor(mx, o, 64));
  __shared__ float red[8];
  if ((t & 63) == 0) red[t >> 6] = mx;
  __syncthreads();
  mx = fmaxf(fmaxf(red[0], red[1]), fmaxf(red[2], red[3]));
  float e[8], sum = 0.f;
#pragma unroll
  for (int j = 0; j < 8; ++j) { e[j] = __expf(x[j] - mx); sum += e[j]; }
#pragma unroll
  for (int o = 32; o >= 1; o >>= 1) sum += __shfl_xor(sum, o, 64);
  if ((t & 63) == 0) red[4 + (t >> 6)] = sum;
  __syncthreads();
  float inv = 1.f / (red[4] + red[5] + red[6] + red[7]);
  ushort4 o0 = make_ushort4(f2h(e[0] * inv), f2h(e[1] * inv), f2h(e[2] * inv), f2h(e[3] * inv));
  ushort4 o1 = make_ushort4(f2h(e[4] * inv), f2h(e[5] * inv), f2h(e[6] * inv), f2h(e[7] * inv));
  *(ushort4*)(p + t * 8) = o0;
  *(ushort4*)(p + t * 8 + 4) = o1;
}

extern "C" void kernel_launch(void* const* d_in, const int* in_sizes, int n_in,
                              void* d_out, int out_size, void* d_ws, size_t ws_size,
                              hipStream_t stream) {
  const float* query = (const float*)d_in[0];
  const float* mem = (const float*)d_in[1];
  const int* mask = (const int*)d_in[2];
  const float* Wm = (const float*)d_in[3];
  const float* bias = (const float*)d_in[4];
  float* out = (float*)d_out;   // fp32 output

  const long nQ = (long)B_ * SQL * DD;   // 16.7M
  const long nW = (long)DD * DD;
  const long nS = (long)B_ * SQL * SKL;

  char* ws = (char*)d_ws;
  u16* qh = (u16*)ws; ws += nQ * 2;
  u16* ql = (u16*)ws; ws += nQ * 2;
  u16* memh = (u16*)ws; ws += nQ * 2;
  u16* memT = (u16*)ws; ws += nQ * 2;
  u16* ph = (u16*)ws; ws += nQ * 2;
  u16* pl = (u16*)ws; ws += nQ * 2;
  u16* wh = (u16*)ws; ws += nW * 2;
  u16* wl = (u16*)ws; ws += nW * 2;
  float* S = (float*)ws; ws += nS * 4;
  u16* P = qh;   // qh+ql (67MB adjacent) dead after projection

  split16_k<<<2048, 256, 0, stream>>>(query, qh, ql, nQ);
  split16_k<<<512, 256, 0, stream>>>(Wm, wh, wl, nW);
  split_mem16_k<<<dim3(DD / 64, SKL / 64, B_), 256, 0, stream>>>(mem, memh, memT);

  // projection (3-term): M=16384, N=D, K=D ; writes q as fp16 hi/lo
  gemm_f16<3, 2, true><<<dim3(DD / 128, (B_ * SQL) / 128, 1), 256, 0, stream>>>(
      qh, ql, wh, wl, bias, ph, pl, DD, DD, 0, 0, 0);
  // logits (2-term): per batch M=Sq, N=Sk, K=D ; fp32 S
  gemm_f16<2, 0, false><<<dim3(SKL / 128, SQL / 128, B_), 256, 0, stream>>>(
      ph, pl, memh, nullptr, nullptr, S, nullptr, SKL, DD,
      (long)SQL * DD, (long)SKL * DD, (long)SQL * SKL);
  // mask + softmax -> P fp16
  softmax16_k<<<B_ * SQL, 256, 0, stream>>>(S, mask, P);
  // PV (1-term): per batch M=Sq, N=D, K=Sk ; B = memT [D][Sk] ; fp32 out
  gemm_f16<1, 0, false><<<dim3(DD / 128, SQL / 128, B_), 256, 0, stream>>>(
      P, nullptr, memT, nullptr, nullptr, out, nullptr, DD, SKL,
      (long)SQL * SKL, (long)DD * SKL, (long)SQL * DD);
}

// Round 14
// 511.532 us; speedup vs baseline: 1.4579x; 1.4579x over previous
//
#include <hip/hip_runtime.h>

// Round 14: R13 fp16 pipeline with the launch-bounds bug fixed:
// __launch_bounds__(256,4) capped VGPR at 64 -> acc alone spilled ->
// 1.7GB scratch traffic/dispatch, MfmaUtil 10.5%. Back to (256,2)
// (the R9-R12 proven setting: 80 VGPR, zero spill). Numerics validated
// by R13: absmax 0.0391.
//  - proj: 3-term fp16 -> q hi/lo
//  - QK:   2-term fp16 (qh+ql) x memh, B LDS halved (24KB total)
//  - PV:   1-term fp16 P x memT

typedef __attribute__((ext_vector_type(8))) _Float16 f16x8;
typedef __attribute__((ext_vector_type(4))) float f32x4;
typedef unsigned short u16;
typedef unsigned int u32;

#define B_ 8
#define SQL 2048
#define SKL 2048
#define DD 1024
#define NEGC -1000000000.0f

static __device__ __forceinline__ u16 f2h(float x) {
  _Float16 h = (_Float16)x;                       // v_cvt_f16_f32, RNE
  return __builtin_bit_cast(u16, h);
}
static __device__ __forceinline__ float h2f(u16 v) {
  return (float)__builtin_bit_cast(_Float16, v);
}
static __device__ __forceinline__ void gload16(const void* g, void* l) {
  __builtin_amdgcn_global_load_lds((const __attribute__((address_space(1))) u32*)g,
                                   (__attribute__((address_space(3))) u32*)l, 16, 0, 0);
}

// ---------------- split fp32 -> fp16 hi + fp16 lo ----------------
__global__ __launch_bounds__(256) void split16_k(const float* __restrict__ in,
                                                 u16* __restrict__ hi, u16* __restrict__ lo,
                                                 long n) {
  long i = ((long)blockIdx.x * 256 + threadIdx.x) * 4;
  long stride = (long)gridDim.x * 256 * 4;
  for (; i < n; i += stride) {
    float4 v = *(const float4*)(in + i);
    u16 h0 = f2h(v.x), h1 = f2h(v.y), h2 = f2h(v.z), h3 = f2h(v.w);
    *(ushort4*)(hi + i) = make_ushort4(h0, h1, h2, h3);
    *(ushort4*)(lo + i) = make_ushort4(f2h(v.x - h2f(h0)), f2h(v.y - h2f(h1)),
                                       f2h(v.z - h2f(h2)), f2h(v.w - h2f(h3)));
  }
}

// ---------------- fused mem: fp32 [Sk][D] -> memh fp16 + memT fp16 [D][Sk] ----------------
__global__ __launch_bounds__(256) void split_mem16_k(const float* __restrict__ in,
                                                     u16* __restrict__ hi,
                                                     u16* __restrict__ trn) {
  __shared__ u16 t[64][65];
  long bo = (long)blockIdx.z * SKL * DD;
  int r0 = blockIdx.y * 64, c0 = blockIdx.x * 64;
  int tr = threadIdx.x / 16, tc4 = (threadIdx.x % 16) * 4;
#pragma unroll
  for (int i = 0; i < 4; ++i) {
    int r = tr + i * 16;
    long idx = bo + (long)(r0 + r) * DD + c0 + tc4;
    float4 v = *(const float4*)(in + idx);
    u16 h0 = f2h(v.x), h1 = f2h(v.y), h2 = f2h(v.z), h3 = f2h(v.w);
    *(ushort4*)(hi + idx) = make_ushort4(h0, h1, h2, h3);
    t[r][tc4 + 0] = h0; t[r][tc4 + 1] = h1; t[r][tc4 + 2] = h2; t[r][tc4 + 3] = h3;
  }
  __syncthreads();
#pragma unroll
  for (int i = 0; i < 4; ++i) {
    int c = tr + i * 16;   // output row = original column c0+c
    ushort4 v = make_ushort4(t[tc4 + 0][c], t[tc4 + 1][c], t[tc4 + 2][c], t[tc4 + 3][c]);
    *(ushort4*)(trn + bo + (long)(c0 + c) * SKL + r0 + tc4) = v;
  }
}

// ---------------- unified B^T-layout fp16 MFMA GEMM ----------------
// C[m][n] = sum_k A[m][k]*B[n][k]; 128x128 tile, 4 waves (2x2),
// mfma_f32_16x16x32_f16, single-buffer LDS, XOR-swizzled via pre-swizzled
// global source.
// TERMS=3: BK=32, A,B rows 64 u16 (hi 0-3 | lo 4-7).   proj
// TERMS=2: BK=32, A rows 64 u16 (hi|lo), B rows 32 u16 (hi only). QK
// TERMS=1: BK=64, A,B rows 64 u16 (single dtype).      PV
// OUTMODE: 0 = fp32 ; 2 = fp16 hi + lo (to C0,C1)
template <int TERMS, int OUTMODE, bool BIAS>
__global__ __launch_bounds__(256, 2) void gemm_f16(
    const u16* __restrict__ Ah, const u16* __restrict__ Al,
    const u16* __restrict__ Bh, const u16* __restrict__ Bl,
    const float* __restrict__ bias,
    void* __restrict__ C0, void* __restrict__ C1,
    int N, int K, long batchA, long batchB, long batchC) {
  constexpr int KSTEP = (TERMS >= 2) ? 32 : 64;
  constexpr int RWB = (TERMS == 2) ? 32 : 64;   // u16 per B LDS row
  __shared__ u16 lA[128 * 64];
  __shared__ u16 lB[128 * RWB];

  const int bz = blockIdx.z;
  const u16* pAh = Ah + (long)bz * batchA;
  const u16* pBh = Bh + (long)bz * batchB;
  const u16* pAl = (TERMS >= 2) ? (Al + (long)bz * batchA) : nullptr;
  const u16* pBl = (TERMS == 3) ? (Bl + (long)bz * batchB) : nullptr;

  const int tid = threadIdx.x;
  const int l = tid & 63, w = tid >> 6;
  const int wr = w >> 1, wc = w & 1;
  const long am0 = (long)blockIdx.y * 128;
  const long bn0 = (long)blockIdx.x * 128;

  f32x4 acc[4][4];
#pragma unroll
  for (int i = 0; i < 4; ++i)
#pragma unroll
    for (int j = 0; j < 4; ++j) {
      f32x4 z = {0.f, 0.f, 0.f, 0.f};
      acc[i][j] = z;
    }

  const int lrow = l & 15, lch = l >> 4;

  for (int k0 = 0; k0 < K; k0 += KSTEP) {
    __syncthreads();
    // ---- A stage: 8 chunks/row, proven involution ----
#pragma unroll
    for (int i = 0; i < 4; ++i) {
      int row = i * 32 + (tid >> 3);
      int cc = (tid & 7) ^ (row & 7);
      const u16* sA;
      if (TERMS >= 2)
        sA = (cc >= 4) ? (pAl + (am0 + row) * K + k0 + (cc - 4) * 8)
                       : (pAh + (am0 + row) * K + k0 + cc * 8);
      else
        sA = pAh + (am0 + row) * K + k0 + cc * 8;
      gload16(sA, &lA[row * 64 + (tid & 7) * 8]);
    }
    // ---- B stage ----
    if (TERMS == 2) {
#pragma unroll
      for (int i = 0; i < 2; ++i) {
        int row = i * 64 + (tid >> 2);
        int cc = (tid & 3) ^ (row & 3);   // 4-chunk involution
        gload16(pBh + (bn0 + row) * K + k0 + cc * 8, &lB[row * 32 + (tid & 3) * 8]);
      }
    } else {
#pragma unroll
      for (int i = 0; i < 4; ++i) {
        int row = i * 32 + (tid >> 3);
        int cc = (tid & 7) ^ (row & 7);
        const u16* sB;
        if (TERMS == 3)
          sB = (cc >= 4) ? (pBl + (bn0 + row) * K + k0 + (cc - 4) * 8)
                         : (pBh + (bn0 + row) * K + k0 + cc * 8);
        else
          sB = pBh + (bn0 + row) * K + k0 + cc * 8;
        gload16(sB, &lB[row * 64 + (tid & 7) * 8]);
      }
    }
    __syncthreads();

    if (TERMS == 3) {
      f16x8 ah[4], bh[4], al_[4], bl_[4];
#pragma unroll
      for (int f = 0; f < 4; ++f) {
        int ra = wr * 64 + f * 16 + lrow;
        int rb = wc * 64 + f * 16 + lrow;
        ah[f] = *(const f16x8*)&lA[ra * 64 + (lch ^ (ra & 7)) * 8];
        bh[f] = *(const f16x8*)&lB[rb * 64 + (lch ^ (rb & 7)) * 8];
        al_[f] = *(const f16x8*)&lA[ra * 64 + ((4 + lch) ^ (ra & 7)) * 8];
        bl_[f] = *(const f16x8*)&lB[rb * 64 + ((4 + lch) ^ (rb & 7)) * 8];
      }
#pragma unroll
      for (int mf = 0; mf < 4; ++mf)
#pragma unroll
        for (int nf = 0; nf < 4; ++nf) {
          acc[mf][nf] = __builtin_amdgcn_mfma_f32_16x16x32_f16(ah[mf], bh[nf], acc[mf][nf], 0, 0, 0);
          acc[mf][nf] = __builtin_amdgcn_mfma_f32_16x16x32_f16(ah[mf], bl_[nf], acc[mf][nf], 0, 0, 0);
          acc[mf][nf] = __builtin_amdgcn_mfma_f32_16x16x32_f16(al_[mf], bh[nf], acc[mf][nf], 0, 0, 0);
        }
    } else if (TERMS == 2) {
      f16x8 ah[4], al_[4], bh[4];
#pragma unroll
      for (int f = 0; f < 4; ++f) {
        int ra = wr * 64 + f * 16 + lrow;
        int rb = wc * 64 + f * 16 + lrow;
        ah[f] = *(const f16x8*)&lA[ra * 64 + (lch ^ (ra & 7)) * 8];
        al_[f] = *(const f16x8*)&lA[ra * 64 + ((4 + lch) ^ (ra & 7)) * 8];
        bh[f] = *(const f16x8*)&lB[rb * 32 + (lch ^ (rb & 3)) * 8];
      }
#pragma unroll
      for (int mf = 0; mf < 4; ++mf)
#pragma unroll
        for (int nf = 0; nf < 4; ++nf) {
          acc[mf][nf] = __builtin_amdgcn_mfma_f32_16x16x32_f16(ah[mf], bh[nf], acc[mf][nf], 0, 0, 0);
          acc[mf][nf] = __builtin_amdgcn_mfma_f32_16x16x32_f16(al_[mf], bh[nf], acc[mf][nf], 0, 0, 0);
        }
    } else {
#pragma unroll
      for (int kk = 0; kk < 2; ++kk) {
        f16x8 ah[4], bh[4];
#pragma unroll
        for (int f = 0; f < 4; ++f) {
          int ra = wr * 64 + f * 16 + lrow;
          int rb = wc * 64 + f * 16 + lrow;
          int c = kk * 4 + lch;
          ah[f] = *(const f16x8*)&lA[ra * 64 + (c ^ (ra & 7)) * 8];
          bh[f] = *(const f16x8*)&lB[rb * 64 + (c ^ (rb & 7)) * 8];
        }
#pragma unroll
        for (int mf = 0; mf < 4; ++mf)
#pragma unroll
          for (int nf = 0; nf < 4; ++nf)
            acc[mf][nf] = __builtin_amdgcn_mfma_f32_16x16x32_f16(ah[mf], bh[nf], acc[mf][nf], 0, 0, 0);
      }
    }
  }

  // epilogue: C/D layout col = lane&15, row = (lane>>4)*4 + reg
#pragma unroll
  for (int mf = 0; mf < 4; ++mf)
#pragma unroll
    for (int nf = 0; nf < 4; ++nf)
#pragma unroll
      for (int r = 0; r < 4; ++r) {
        long row = am0 + wr * 64 + mf * 16 + (l >> 4) * 4 + r;
        long col = bn0 + wc * 64 + nf * 16 + (l & 15);
        float v = acc[mf][nf][r];
        if (BIAS) v += bias[col];
        long idx = (long)bz * batchC + row * N + col;
        if (OUTMODE == 0) {
          ((float*)C0)[idx] = v;
        } else {
          u16 h = f2h(v);
          ((u16*)C0)[idx] = h;
          ((u16*)C1)[idx] = f2h(v - h2f(h));
        }
      }
}

// ---------------- mask + row softmax: S fp32, mask int32 -> P fp16 ----------------
__global__ __launch_bounds__(256) void softmax16_k(const float* __restrict__ S,
                                                   const int* __restrict__ M,
                                                   u16* __restrict__ P) {
  long row = blockIdx.x;
  const float* s = S + row * SKL;
  const int* m = M + row * SKL;
  u16* p = P + row * SKL;
  int t = threadIdx.x;
  float x[8];
#pragma unroll
  for (int j = 0; j < 2; ++j) {
    float4 v = *(const float4*)(s + t * 8 + j * 4);
    int4 q = *(const int4*)(m + t * 8 + j * 4);
    x[j * 4 + 0] = q.x ? v.x : v.x + NEGC;
    x[j * 4 + 1] = q.y ? v.y : v.y + NEGC;
    x[j * 4 + 2] = q.z ? v.z : v.z + NEGC;
    x[j * 4 + 3] = q.w ? v.w : v.w + NEGC;
  }
  float mx = x[0];
#pragma unroll
  for (int j = 1; j < 8; ++j) mx = fmaxf(mx, x[j]);
#pragma unroll
  for (int o = 32; o >= 1; o >>= 1) mx = fmaxf(mx, __shfl_xor(mx, o, 64));
  __shared__ float red[8];
  if ((t & 63) == 0) red[t >> 6] = mx;
  __syncthreads();
  mx = fmaxf(fmaxf(red[0], red[1]), fmaxf(red[2], red[3]));
  float e[8], sum = 0.f;
#pragma unroll
  for (int j = 0; j < 8; ++j) { e[j] = __expf(x[j] - mx); sum += e[j]; }
#pragma unroll
  for (int o = 32; o >= 1; o >>= 1) sum += __shfl_xor(sum, o, 64);
  if ((t & 63) == 0) red[4 + (t >> 6)] = sum;
  __syncthreads();
  float inv = 1.f / (red[4] + red[5] + red[6] + red[7]);
  ushort4 o0 = make_ushort4(f2h(e[0] * inv), f2h(e[1] * inv), f2h(e[2] * inv), f2h(e[3] * inv));
  ushort4 o1 = make_ushort4(f2h(e[4] * inv), f2h(e[5] * inv), f2h(e[6] * inv), f2h(e[7] * inv));
  *(ushort4*)(p + t * 8) = o0;
  *(ushort4*)(p + t * 8 + 4) = o1;
}

extern "C" void kernel_launch(void* const* d_in, const int* in_sizes, int n_in,
                              void* d_out, int out_size, void* d_ws, size_t ws_size,
                              hipStream_t stream) {
  const float* query = (const float*)d_in[0];
  const float* mem = (const float*)d_in[1];
  const int* mask = (const int*)d_in[2];
  const float* Wm = (const float*)d_in[3];
  const float* bias = (const float*)d_in[4];
  float* out = (float*)d_out;   // fp32 output

  const long nQ = (long)B_ * SQL * DD;   // 16.7M
  const long nW = (long)DD * DD;
  const long nS = (long)B_ * SQL * SKL;

  char* ws = (char*)d_ws;
  u16* qh = (u16*)ws; ws += nQ * 2;
  u16* ql = (u16*)ws; ws += nQ * 2;
  u16* memh = (u16*)ws; ws += nQ * 2;
  u16* memT = (u16*)ws; ws += nQ * 2;
  u16* ph = (u16*)ws; ws += nQ * 2;
  u16* pl = (u16*)ws; ws += nQ * 2;
  u16* wh = (u16*)ws; ws += nW * 2;
  u16* wl = (u16*)ws; ws += nW * 2;
  float* S = (float*)ws; ws += nS * 4;
  u16* P = qh;   // qh+ql (67MB adjacent) dead after projection

  split16_k<<<2048, 256, 0, stream>>>(query, qh, ql, nQ);
  split16_k<<<512, 256, 0, stream>>>(Wm, wh, wl, nW);
  split_mem16_k<<<dim3(DD / 64, SKL / 64, B_), 256, 0, stream>>>(mem, memh, memT);

  // projection (3-term): M=16384, N=D, K=D ; writes q as fp16 hi/lo
  gemm_f16<3, 2, true><<<dim3(DD / 128, (B_ * SQL) / 128, 1), 256, 0, stream>>>(
      qh, ql, wh, wl, bias, ph, pl, DD, DD, 0, 0, 0);
  // logits (2-term): per batch M=Sq, N=Sk, K=D ; fp32 S
  gemm_f16<2, 0, false><<<dim3(SKL / 128, SQL / 128, B_), 256, 0, stream>>>(
      ph, pl, memh, nullptr, nullptr, S, nullptr, SKL, DD,
      (long)SQL * DD, (long)SKL * DD, (long)SQL * SKL);
  // mask + softmax -> P fp16
  softmax16_k<<<B_ * SQL, 256, 0, stream>>>(S, mask, P);
  // PV (1-term): per batch M=Sq, N=D, K=Sk ; B = memT [D][Sk] ; fp32 out
  gemm_f16<1, 0, false><<<dim3(DD / 128, SQL / 128, B_), 256, 0, stream>>>(
      P, nullptr, memT, nullptr, nullptr, out, nullptr, DD, SKL,
      (long)SQL * SKL, (long)DD * SKL, (long)SQL * DD);
}

// Round 15
// 425.189 us; speedup vs baseline: 1.7539x; 1.2031x over previous
//
#include <hip/hip_runtime.h>

// Round 15: 1-term fp16 QK. Error budget: dropping q_lo*mem_h adds only sqrt(2)
// vs R14's 2-term (each cross term ~9e-3 logit noise; measured absmax 0.039 was
// PV-rounding dominated). QK becomes the proven TERMS=1 BK=64 conflict-free
// config (R14's 2-term B-tile had 4.19M bank conflicts from 64B row stride).
// proj now emits q as single fp16 (OUTMODE=1). Everything else = R14.

typedef __attribute__((ext_vector_type(8))) _Float16 f16x8;
typedef __attribute__((ext_vector_type(4))) float f32x4;
typedef unsigned short u16;
typedef unsigned int u32;

#define B_ 8
#define SQL 2048
#define SKL 2048
#define DD 1024
#define NEGC -1000000000.0f

static __device__ __forceinline__ u16 f2h(float x) {
  _Float16 h = (_Float16)x;                       // v_cvt_f16_f32, RNE
  return __builtin_bit_cast(u16, h);
}
static __device__ __forceinline__ float h2f(u16 v) {
  return (float)__builtin_bit_cast(_Float16, v);
}
static __device__ __forceinline__ void gload16(const void* g, void* l) {
  __builtin_amdgcn_global_load_lds((const __attribute__((address_space(1))) u32*)g,
                                   (__attribute__((address_space(3))) u32*)l, 16, 0, 0);
}

// ---------------- split fp32 -> fp16 hi + fp16 lo ----------------
__global__ __launch_bounds__(256) void split16_k(const float* __restrict__ in,
                                                 u16* __restrict__ hi, u16* __restrict__ lo,
                                                 long n) {
  long i = ((long)blockIdx.x * 256 + threadIdx.x) * 4;
  long stride = (long)gridDim.x * 256 * 4;
  for (; i < n; i += stride) {
    float4 v = *(const float4*)(in + i);
    u16 h0 = f2h(v.x), h1 = f2h(v.y), h2 = f2h(v.z), h3 = f2h(v.w);
    *(ushort4*)(hi + i) = make_ushort4(h0, h1, h2, h3);
    *(ushort4*)(lo + i) = make_ushort4(f2h(v.x - h2f(h0)), f2h(v.y - h2f(h1)),
                                       f2h(v.z - h2f(h2)), f2h(v.w - h2f(h3)));
  }
}

// ---------------- fused mem: fp32 [Sk][D] -> memh fp16 + memT fp16 [D][Sk] ----------------
__global__ __launch_bounds__(256) void split_mem16_k(const float* __restrict__ in,
                                                     u16* __restrict__ hi,
                                                     u16* __restrict__ trn) {
  __shared__ u16 t[64][65];
  long bo = (long)blockIdx.z * SKL * DD;
  int r0 = blockIdx.y * 64, c0 = blockIdx.x * 64;
  int tr = threadIdx.x / 16, tc4 = (threadIdx.x % 16) * 4;
#pragma unroll
  for (int i = 0; i < 4; ++i) {
    int r = tr + i * 16;
    long idx = bo + (long)(r0 + r) * DD + c0 + tc4;
    float4 v = *(const float4*)(in + idx);
    u16 h0 = f2h(v.x), h1 = f2h(v.y), h2 = f2h(v.z), h3 = f2h(v.w);
    *(ushort4*)(hi + idx) = make_ushort4(h0, h1, h2, h3);
    t[r][tc4 + 0] = h0; t[r][tc4 + 1] = h1; t[r][tc4 + 2] = h2; t[r][tc4 + 3] = h3;
  }
  __syncthreads();
#pragma unroll
  for (int i = 0; i < 4; ++i) {
    int c = tr + i * 16;   // output row = original column c0+c
    ushort4 v = make_ushort4(t[tc4 + 0][c], t[tc4 + 1][c], t[tc4 + 2][c], t[tc4 + 3][c]);
    *(ushort4*)(trn + bo + (long)(c0 + c) * SKL + r0 + tc4) = v;
  }
}

// ---------------- unified B^T-layout fp16 MFMA GEMM ----------------
// C[m][n] = sum_k A[m][k]*B[n][k]; 128x128 tile, 4 waves (2x2),
// mfma_f32_16x16x32_f16, single-buffer LDS (32KB), XOR-swizzled via
// pre-swizzled global source.
// TERMS=3: BK=32, A,B rows 64 u16 (hi 0-3 | lo 4-7).   proj
// TERMS=1: BK=64, A,B rows 64 u16 (single dtype).      QK + PV
// OUTMODE: 0 = fp32 ; 1 = fp16 single ; 2 = fp16 hi + lo
template <int TERMS, int OUTMODE, bool BIAS>
__global__ __launch_bounds__(256, 2) void gemm_f16(
    const u16* __restrict__ Ah, const u16* __restrict__ Al,
    const u16* __restrict__ Bh, const u16* __restrict__ Bl,
    const float* __restrict__ bias,
    void* __restrict__ C0, void* __restrict__ C1,
    int N, int K, long batchA, long batchB, long batchC) {
  constexpr int KSTEP = (TERMS > 1) ? 32 : 64;
  __shared__ u16 lA[128 * 64];
  __shared__ u16 lB[128 * 64];

  const int bz = blockIdx.z;
  const u16* pAh = Ah + (long)bz * batchA;
  const u16* pBh = Bh + (long)bz * batchB;
  const u16* pAl = (TERMS > 1) ? (Al + (long)bz * batchA) : nullptr;
  const u16* pBl = (TERMS > 1) ? (Bl + (long)bz * batchB) : nullptr;

  const int tid = threadIdx.x;
  const int l = tid & 63, w = tid >> 6;
  const int wr = w >> 1, wc = w & 1;
  const long am0 = (long)blockIdx.y * 128;
  const long bn0 = (long)blockIdx.x * 128;

  f32x4 acc[4][4];
#pragma unroll
  for (int i = 0; i < 4; ++i)
#pragma unroll
    for (int j = 0; j < 4; ++j) {
      f32x4 z = {0.f, 0.f, 0.f, 0.f};
      acc[i][j] = z;
    }

  const int lrow = l & 15, lch = l >> 4;

  for (int k0 = 0; k0 < K; k0 += KSTEP) {
    __syncthreads();
#pragma unroll
    for (int i = 0; i < 4; ++i) {
      int row = i * 32 + (tid >> 3);
      int cc = (tid & 7) ^ (row & 7);   // logical chunk living at dest slot
      const u16* sA;
      const u16* sB;
      if (TERMS > 1 && cc >= 4) {
        sA = pAl + (am0 + row) * K + k0 + (cc - 4) * 8;
        sB = pBl + (bn0 + row) * K + k0 + (cc - 4) * 8;
      } else {
        sA = pAh + (am0 + row) * K + k0 + (TERMS > 1 ? (cc & 3) : cc) * 8;
        sB = pBh + (bn0 + row) * K + k0 + (TERMS > 1 ? (cc & 3) : cc) * 8;
      }
      gload16(sA, &lA[row * 64 + (tid & 7) * 8]);
      gload16(sB, &lB[row * 64 + (tid & 7) * 8]);
    }
    __syncthreads();

    if (TERMS > 1) {
      f16x8 ah[4], bh[4], al_[4], bl_[4];
#pragma unroll
      for (int f = 0; f < 4; ++f) {
        int ra = wr * 64 + f * 16 + lrow;
        int rb = wc * 64 + f * 16 + lrow;
        ah[f] = *(const f16x8*)&lA[ra * 64 + (lch ^ (ra & 7)) * 8];
        bh[f] = *(const f16x8*)&lB[rb * 64 + (lch ^ (rb & 7)) * 8];
        al_[f] = *(const f16x8*)&lA[ra * 64 + ((4 + lch) ^ (ra & 7)) * 8];
        bl_[f] = *(const f16x8*)&lB[rb * 64 + ((4 + lch) ^ (rb & 7)) * 8];
      }
#pragma unroll
      for (int mf = 0; mf < 4; ++mf)
#pragma unroll
        for (int nf = 0; nf < 4; ++nf) {
          acc[mf][nf] = __builtin_amdgcn_mfma_f32_16x16x32_f16(ah[mf], bh[nf], acc[mf][nf], 0, 0, 0);
          acc[mf][nf] = __builtin_amdgcn_mfma_f32_16x16x32_f16(ah[mf], bl_[nf], acc[mf][nf], 0, 0, 0);
          acc[mf][nf] = __builtin_amdgcn_mfma_f32_16x16x32_f16(al_[mf], bh[nf], acc[mf][nf], 0, 0, 0);
        }
    } else {
#pragma unroll
      for (int kk = 0; kk < 2; ++kk) {
        f16x8 ah[4], bh[4];
#pragma unroll
        for (int f = 0; f < 4; ++f) {
          int ra = wr * 64 + f * 16 + lrow;
          int rb = wc * 64 + f * 16 + lrow;
          int c = kk * 4 + lch;
          ah[f] = *(const f16x8*)&lA[ra * 64 + (c ^ (ra & 7)) * 8];
          bh[f] = *(const f16x8*)&lB[rb * 64 + (c ^ (rb & 7)) * 8];
        }
#pragma unroll
        for (int mf = 0; mf < 4; ++mf)
#pragma unroll
          for (int nf = 0; nf < 4; ++nf)
            acc[mf][nf] = __builtin_amdgcn_mfma_f32_16x16x32_f16(ah[mf], bh[nf], acc[mf][nf], 0, 0, 0);
      }
    }
  }

  // epilogue: C/D layout col = lane&15, row = (lane>>4)*4 + reg
#pragma unroll
  for (int mf = 0; mf < 4; ++mf)
#pragma unroll
    for (int nf = 0; nf < 4; ++nf)
#pragma unroll
      for (int r = 0; r < 4; ++r) {
        long row = am0 + wr * 64 + mf * 16 + (l >> 4) * 4 + r;
        long col = bn0 + wc * 64 + nf * 16 + (l & 15);
        float v = acc[mf][nf][r];
        if (BIAS) v += bias[col];
        long idx = (long)bz * batchC + row * N + col;
        if (OUTMODE == 0) {
          ((float*)C0)[idx] = v;
        } else if (OUTMODE == 1) {
          ((u16*)C0)[idx] = f2h(v);
        } else {
          u16 h = f2h(v);
          ((u16*)C0)[idx] = h;
          ((u16*)C1)[idx] = f2h(v - h2f(h));
        }
      }
}

// ---------------- mask + row softmax: S fp32, mask int32 -> P fp16 ----------------
__global__ __launch_bounds__(256) void softmax16_k(const float* __restrict__ S,
                                                   const int* __restrict__ M,
                                                   u16* __restrict__ P) {
  long row = blockIdx.x;
  const float* s = S + row * SKL;
  const int* m = M + row * SKL;
  u16* p = P + row * SKL;
  int t = threadIdx.x;
  float x[8];
#pragma unroll
  for (int j = 0; j < 2; ++j) {
    float4 v = *(const float4*)(s + t * 8 + j * 4);
    int4 q = *(const int4*)(m + t * 8 + j * 4);
    x[j * 4 + 0] = q.x ? v.x : v.x + NEGC;
    x[j * 4 + 1] = q.y ? v.y : v.y + NEGC;
    x[j * 4 + 2] = q.z ? v.z : v.z + NEGC;
    x[j * 4 + 3] = q.w ? v.w : v.w + NEGC;
  }
  float mx = x[0];
#pragma unroll
  for (int j = 1; j < 8; ++j) mx = fmaxf(mx, x[j]);
#pragma unroll
  for (int o = 32; o >= 1; o >>= 1) mx = fmaxf(mx, __shfl_xor(mx, o, 64));
  __shared__ float red[8];
  if ((t & 63) == 0) red[t >> 6] = mx;
  __syncthreads();
  mx = fmaxf(fmaxf(red[0], red[1]), fmaxf(red[2], red[3]));
  float e[8], sum = 0.f;
#pragma unroll
  for (int j = 0; j < 8; ++j) { e[j] = __expf(x[j] - mx); sum += e[j]; }
#pragma unroll
  for (int o = 32; o >= 1; o >>= 1) sum += __shfl_xor(sum, o, 64);
  if ((t & 63) == 0) red[4 + (t >> 6)] = sum;
  __syncthreads();
  float inv = 1.f / (red[4] + red[5] + red[6] + red[7]);
  ushort4 o0 = make_ushort4(f2h(e[0] * inv), f2h(e[1] * inv), f2h(e[2] * inv), f2h(e[3] * inv));
  ushort4 o1 = make_ushort4(f2h(e[4] * inv), f2h(e[5] * inv), f2h(e[6] * inv), f2h(e[7] * inv));
  *(ushort4*)(p + t * 8) = o0;
  *(ushort4*)(p + t * 8 + 4) = o1;
}

extern "C" void kernel_launch(void* const* d_in, const int* in_sizes, int n_in,
                              void* d_out, int out_size, void* d_ws, size_t ws_size,
                              hipStream_t stream) {
  const float* query = (const float*)d_in[0];
  const float* mem = (const float*)d_in[1];
  const int* mask = (const int*)d_in[2];
  const float* Wm = (const float*)d_in[3];
  const float* bias = (const float*)d_in[4];
  float* out = (float*)d_out;   // fp32 output

  const long nQ = (long)B_ * SQL * DD;   // 16.7M
  const long nW = (long)DD * DD;
  const long nS = (long)B_ * SQL * SKL;

  char* ws = (char*)d_ws;
  u16* qh = (u16*)ws; ws += nQ * 2;
  u16* ql = (u16*)ws; ws += nQ * 2;
  u16* memh = (u16*)ws; ws += nQ * 2;
  u16* memT = (u16*)ws; ws += nQ * 2;
  u16* q1 = (u16*)ws; ws += nQ * 2;    // projected q, single fp16
  u16* wh = (u16*)ws; ws += nW * 2;
  u16* wl = (u16*)ws; ws += nW * 2;
  float* S = (float*)ws; ws += nS * 4;
  u16* P = qh;   // qh+ql (67MB adjacent) dead after projection

  split16_k<<<2048, 256, 0, stream>>>(query, qh, ql, nQ);
  split16_k<<<512, 256, 0, stream>>>(Wm, wh, wl, nW);
  split_mem16_k<<<dim3(DD / 64, SKL / 64, B_), 256, 0, stream>>>(mem, memh, memT);

  // projection (3-term): M=16384, N=D, K=D ; q -> single fp16
  gemm_f16<3, 1, true><<<dim3(DD / 128, (B_ * SQL) / 128, 1), 256, 0, stream>>>(
      qh, ql, wh, wl, bias, q1, nullptr, DD, DD, 0, 0, 0);
  // logits (1-term): per batch M=Sq, N=Sk, K=D ; fp32 S
  gemm_f16<1, 0, false><<<dim3(SKL / 128, SQL / 128, B_), 256, 0, stream>>>(
      q1, nullptr, memh, nullptr, nullptr, S, nullptr, SKL, DD,
      (long)SQL * DD, (long)SKL * DD, (long)SQL * SKL);
  // mask + softmax -> P fp16
  softmax16_k<<<B_ * SQL, 256, 0, stream>>>(S, mask, P);
  // PV (1-term): per batch M=Sq, N=D, K=Sk ; B = memT [D][Sk] ; fp32 out
  gemm_f16<1, 0, false><<<dim3(DD / 128, SQL / 128, B_), 256, 0, stream>>>(
      P, nullptr, memT, nullptr, nullptr, out, nullptr, DD, SKL,
      (long)SQL * SKL, (long)DD * SKL, (long)SQL * DD);
}

// Round 16
// 371.994 us; speedup vs baseline: 2.0047x; 1.1430x over previous
//
#include <hip/hip_runtime.h>

// Round 16: 2-term proj = fp16(query) x (Wh + Wl). Error budget: query-rounding
// noise (5.1e-3) < existing QK fp16 noise (7.4e-3 each side); total logit sigma
// +12% -> absmax ~0.05 (threshold 0.108). proj 103->69 GF; query split becomes
// plain fp32->fp16 convert. New TERMS=2 B-layout: BK=64, 16-chunk rows
// (Wh 0-7 | Wl 8-15), slot = chunk ^ (row&15) involution (2-way banks = free).
// QK/PV/softmax/mem-split unchanged from R15 (425 us, absmax 0.0488).

typedef __attribute__((ext_vector_type(8))) _Float16 f16x8;
typedef __attribute__((ext_vector_type(4))) float f32x4;
typedef unsigned short u16;
typedef unsigned int u32;

#define B_ 8
#define SQL 2048
#define SKL 2048
#define DD 1024
#define NEGC -1000000000.0f

static __device__ __forceinline__ u16 f2h(float x) {
  _Float16 h = (_Float16)x;                       // v_cvt_f16_f32, RNE
  return __builtin_bit_cast(u16, h);
}
static __device__ __forceinline__ float h2f(u16 v) {
  return (float)__builtin_bit_cast(_Float16, v);
}
static __device__ __forceinline__ void gload16(const void* g, void* l) {
  __builtin_amdgcn_global_load_lds((const __attribute__((address_space(1))) u32*)g,
                                   (__attribute__((address_space(3))) u32*)l, 16, 0, 0);
}

// ---------------- convert fp32 -> fp16 (single) ----------------
__global__ __launch_bounds__(256) void cvt16_k(const float* __restrict__ in,
                                               u16* __restrict__ out, long n) {
  long i = ((long)blockIdx.x * 256 + threadIdx.x) * 8;
  long stride = (long)gridDim.x * 256 * 8;
  for (; i < n; i += stride) {
    float4 v0 = *(const float4*)(in + i);
    float4 v1 = *(const float4*)(in + i + 4);
    ushort4 o0 = make_ushort4(f2h(v0.x), f2h(v0.y), f2h(v0.z), f2h(v0.w));
    ushort4 o1 = make_ushort4(f2h(v1.x), f2h(v1.y), f2h(v1.z), f2h(v1.w));
    *(ushort4*)(out + i) = o0;
    *(ushort4*)(out + i + 4) = o1;
  }
}

// ---------------- split fp32 -> fp16 hi + fp16 lo (for W) ----------------
__global__ __launch_bounds__(256) void split16_k(const float* __restrict__ in,
                                                 u16* __restrict__ hi, u16* __restrict__ lo,
                                                 long n) {
  long i = ((long)blockIdx.x * 256 + threadIdx.x) * 4;
  long stride = (long)gridDim.x * 256 * 4;
  for (; i < n; i += stride) {
    float4 v = *(const float4*)(in + i);
    u16 h0 = f2h(v.x), h1 = f2h(v.y), h2 = f2h(v.z), h3 = f2h(v.w);
    *(ushort4*)(hi + i) = make_ushort4(h0, h1, h2, h3);
    *(ushort4*)(lo + i) = make_ushort4(f2h(v.x - h2f(h0)), f2h(v.y - h2f(h1)),
                                       f2h(v.z - h2f(h2)), f2h(v.w - h2f(h3)));
  }
}

// ---------------- fused mem: fp32 [Sk][D] -> memh fp16 + memT fp16 [D][Sk] ----------------
__global__ __launch_bounds__(256) void split_mem16_k(const float* __restrict__ in,
                                                     u16* __restrict__ hi,
                                                     u16* __restrict__ trn) {
  __shared__ u16 t[64][65];
  long bo = (long)blockIdx.z * SKL * DD;
  int r0 = blockIdx.y * 64, c0 = blockIdx.x * 64;
  int tr = threadIdx.x / 16, tc4 = (threadIdx.x % 16) * 4;
#pragma unroll
  for (int i = 0; i < 4; ++i) {
    int r = tr + i * 16;
    long idx = bo + (long)(r0 + r) * DD + c0 + tc4;
    float4 v = *(const float4*)(in + idx);
    u16 h0 = f2h(v.x), h1 = f2h(v.y), h2 = f2h(v.z), h3 = f2h(v.w);
    *(ushort4*)(hi + idx) = make_ushort4(h0, h1, h2, h3);
    t[r][tc4 + 0] = h0; t[r][tc4 + 1] = h1; t[r][tc4 + 2] = h2; t[r][tc4 + 3] = h3;
  }
  __syncthreads();
#pragma unroll
  for (int i = 0; i < 4; ++i) {
    int c = tr + i * 16;   // output row = original column c0+c
    ushort4 v = make_ushort4(t[tc4 + 0][c], t[tc4 + 1][c], t[tc4 + 2][c], t[tc4 + 3][c]);
    *(ushort4*)(trn + bo + (long)(c0 + c) * SKL + r0 + tc4) = v;
  }
}

// ---------------- unified B^T-layout fp16 MFMA GEMM ----------------
// C[m][n] = sum_k A[m][k]*B[n][k]; 128x128 tile, 4 waves (2x2), BK=64,
// mfma_f32_16x16x32_f16, single-buffer LDS, XOR-swizzled via pre-swizzled
// global source. A always single fp16, 8-chunk 128B rows.
// TERMS=2: B dual (Bh|Bl), 16-chunk 256B rows, acc += A*Bh + A*Bl.  proj
// TERMS=1: B single, 8-chunk rows.                                  QK/PV
// OUTMODE: 0 = fp32 ; 1 = fp16 single
template <int TERMS, int OUTMODE, bool BIAS>
__global__ __launch_bounds__(256, 2) void gemm_f16(
    const u16* __restrict__ Ah,
    const u16* __restrict__ Bh, const u16* __restrict__ Bl,
    const float* __restrict__ bias,
    void* __restrict__ C0,
    int N, int K, long batchA, long batchB, long batchC) {
  constexpr int RWB = (TERMS == 2) ? 128 : 64;   // u16 per B LDS row
  __shared__ u16 lA[128 * 64];
  __shared__ u16 lB[128 * RWB];

  const int bz = blockIdx.z;
  const u16* pAh = Ah + (long)bz * batchA;
  const u16* pBh = Bh + (long)bz * batchB;
  const u16* pBl = (TERMS == 2) ? Bl : nullptr;   // proj W has no batch

  const int tid = threadIdx.x;
  const int l = tid & 63, w = tid >> 6;
  const int wr = w >> 1, wc = w & 1;
  const long am0 = (long)blockIdx.y * 128;
  const long bn0 = (long)blockIdx.x * 128;

  f32x4 acc[4][4];
#pragma unroll
  for (int i = 0; i < 4; ++i)
#pragma unroll
    for (int j = 0; j < 4; ++j) {
      f32x4 z = {0.f, 0.f, 0.f, 0.f};
      acc[i][j] = z;
    }

  const int lrow = l & 15, lch = l >> 4;

  for (int k0 = 0; k0 < K; k0 += 64) {
    __syncthreads();
    // ---- A stage: single fp16, 8 chunks/row (proven involution) ----
#pragma unroll
    for (int i = 0; i < 4; ++i) {
      int row = i * 32 + (tid >> 3);
      int cc = (tid & 7) ^ (row & 7);
      gload16(pAh + (am0 + row) * K + k0 + cc * 8, &lA[row * 64 + (tid & 7) * 8]);
    }
    // ---- B stage ----
    if (TERMS == 2) {
      // dual: 16 chunks/row (Bh 0-7 | Bl 8-15), slot = chunk ^ (row&15)
#pragma unroll
      for (int i = 0; i < 8; ++i) {
        int row = i * 16 + (tid >> 4);
        int s = tid & 15;
        int cc = s ^ (row & 15);
        const u16* src = (cc < 8) ? (pBh + (bn0 + row) * K + k0 + cc * 8)
                                  : (pBl + (bn0 + row) * K + k0 + (cc - 8) * 8);
        gload16(src, &lB[row * 128 + s * 8]);
      }
    } else {
#pragma unroll
      for (int i = 0; i < 4; ++i) {
        int row = i * 32 + (tid >> 3);
        int cc = (tid & 7) ^ (row & 7);
        gload16(pBh + (bn0 + row) * K + k0 + cc * 8, &lB[row * 64 + (tid & 7) * 8]);
      }
    }
    __syncthreads();

#pragma unroll
    for (int kk = 0; kk < 2; ++kk) {
      if (TERMS == 2) {
        f16x8 ah[4], bh[4], bl_[4];
#pragma unroll
        for (int f = 0; f < 4; ++f) {
          int ra = wr * 64 + f * 16 + lrow;
          int rb = wc * 64 + f * 16 + lrow;
          int c = kk * 4 + lch;
          ah[f] = *(const f16x8*)&lA[ra * 64 + (c ^ (ra & 7)) * 8];
          bh[f] = *(const f16x8*)&lB[rb * 128 + (c ^ (rb & 15)) * 8];
          bl_[f] = *(const f16x8*)&lB[rb * 128 + ((8 + c) ^ (rb & 15)) * 8];
        }
#pragma unroll
        for (int mf = 0; mf < 4; ++mf)
#pragma unroll
          for (int nf = 0; nf < 4; ++nf) {
            acc[mf][nf] = __builtin_amdgcn_mfma_f32_16x16x32_f16(ah[mf], bh[nf], acc[mf][nf], 0, 0, 0);
            acc[mf][nf] = __builtin_amdgcn_mfma_f32_16x16x32_f16(ah[mf], bl_[nf], acc[mf][nf], 0, 0, 0);
          }
      } else {
        f16x8 ah[4], bh[4];
#pragma unroll
        for (int f = 0; f < 4; ++f) {
          int ra = wr * 64 + f * 16 + lrow;
          int rb = wc * 64 + f * 16 + lrow;
          int c = kk * 4 + lch;
          ah[f] = *(const f16x8*)&lA[ra * 64 + (c ^ (ra & 7)) * 8];
          bh[f] = *(const f16x8*)&lB[rb * 64 + (c ^ (rb & 7)) * 8];
        }
#pragma unroll
        for (int mf = 0; mf < 4; ++mf)
#pragma unroll
          for (int nf = 0; nf < 4; ++nf)
            acc[mf][nf] = __builtin_amdgcn_mfma_f32_16x16x32_f16(ah[mf], bh[nf], acc[mf][nf], 0, 0, 0);
      }
    }
  }

  // epilogue: C/D layout col = lane&15, row = (lane>>4)*4 + reg
#pragma unroll
  for (int mf = 0; mf < 4; ++mf)
#pragma unroll
    for (int nf = 0; nf < 4; ++nf)
#pragma unroll
      for (int r = 0; r < 4; ++r) {
        long row = am0 + wr * 64 + mf * 16 + (l >> 4) * 4 + r;
        long col = bn0 + wc * 64 + nf * 16 + (l & 15);
        float v = acc[mf][nf][r];
        if (BIAS) v += bias[col];
        long idx = (long)bz * batchC + row * N + col;
        if (OUTMODE == 0) ((float*)C0)[idx] = v;
        else              ((u16*)C0)[idx] = f2h(v);
      }
}

// ---------------- mask + row softmax: S fp32, mask int32 -> P fp16 ----------------
__global__ __launch_bounds__(256) void softmax16_k(const float* __restrict__ S,
                                                   const int* __restrict__ M,
                                                   u16* __restrict__ P) {
  long row = blockIdx.x;
  const float* s = S + row * SKL;
  const int* m = M + row * SKL;
  u16* p = P + row * SKL;
  int t = threadIdx.x;
  float x[8];
#pragma unroll
  for (int j = 0; j < 2; ++j) {
    float4 v = *(const float4*)(s + t * 8 + j * 4);
    int4 q = *(const int4*)(m + t * 8 + j * 4);
    x[j * 4 + 0] = q.x ? v.x : v.x + NEGC;
    x[j * 4 + 1] = q.y ? v.y : v.y + NEGC;
    x[j * 4 + 2] = q.z ? v.z : v.z + NEGC;
    x[j * 4 + 3] = q.w ? v.w : v.w + NEGC;
  }
  float mx = x[0];
#pragma unroll
  for (int j = 1; j < 8; ++j) mx = fmaxf(mx, x[j]);
#pragma unroll
  for (int o = 32; o >= 1; o >>= 1) mx = fmaxf(mx, __shfl_xor(mx, o, 64));
  __shared__ float red[8];
  if ((t & 63) == 0) red[t >> 6] = mx;
  __syncthreads();
  mx = fmaxf(fmaxf(red[0], red[1]), fmaxf(red[2], red[3]));
  float e[8], sum = 0.f;
#pragma unroll
  for (int j = 0; j < 8; ++j) { e[j] = __expf(x[j] - mx); sum += e[j]; }
#pragma unroll
  for (int o = 32; o >= 1; o >>= 1) sum += __shfl_xor(sum, o, 64);
  if ((t & 63) == 0) red[4 + (t >> 6)] = sum;
  __syncthreads();
  float inv = 1.f / (red[4] + red[5] + red[6] + red[7]);
  ushort4 o0 = make_ushort4(f2h(e[0] * inv), f2h(e[1] * inv), f2h(e[2] * inv), f2h(e[3] * inv));
  ushort4 o1 = make_ushort4(f2h(e[4] * inv), f2h(e[5] * inv), f2h(e[6] * inv), f2h(e[7] * inv));
  *(ushort4*)(p + t * 8) = o0;
  *(ushort4*)(p + t * 8 + 4) = o1;
}

extern "C" void kernel_launch(void* const* d_in, const int* in_sizes, int n_in,
                              void* d_out, int out_size, void* d_ws, size_t ws_size,
                              hipStream_t stream) {
  const float* query = (const float*)d_in[0];
  const float* mem = (const float*)d_in[1];
  const int* mask = (const int*)d_in[2];
  const float* Wm = (const float*)d_in[3];
  const float* bias = (const float*)d_in[4];
  float* out = (float*)d_out;   // fp32 output

  const long nQ = (long)B_ * SQL * DD;   // 16.7M
  const long nW = (long)DD * DD;
  const long nS = (long)B_ * SQL * SKL;

  char* ws = (char*)d_ws;
  u16* q16 = (u16*)ws; ws += nQ * 2;    // fp16(query); becomes P after proj+QK
  u16* memh = (u16*)ws; ws += nQ * 2;
  u16* memT = (u16*)ws; ws += nQ * 2;
  u16* q1 = (u16*)ws; ws += nQ * 2;     // projected q, fp16
  u16* wh = (u16*)ws; ws += nW * 2;
  u16* wl = (u16*)ws; ws += nW * 2;
  float* S = (float*)ws; ws += nS * 4;
  u16* P = q16;   // q16 dead after projection

  cvt16_k<<<2048, 256, 0, stream>>>(query, q16, nQ);
  split16_k<<<512, 256, 0, stream>>>(Wm, wh, wl, nW);
  split_mem16_k<<<dim3(DD / 64, SKL / 64, B_), 256, 0, stream>>>(mem, memh, memT);

  // projection (2-term): M=16384, N=D, K=D ; q -> fp16
  gemm_f16<2, 1, true><<<dim3(DD / 128, (B_ * SQL) / 128, 1), 256, 0, stream>>>(
      q16, wh, wl, bias, q1, DD, DD, 0, 0, 0);
  // logits (1-term): per batch M=Sq, N=Sk, K=D ; fp32 S
  gemm_f16<1, 0, false><<<dim3(SKL / 128, SQL / 128, B_), 256, 0, stream>>>(
      q1, memh, nullptr, nullptr, S, SKL, DD,
      (long)SQL * DD, (long)SKL * DD, (long)SQL * SKL);
  // mask + softmax -> P fp16
  softmax16_k<<<B_ * SQL, 256, 0, stream>>>(S, mask, P);
  // PV (1-term): per batch M=Sq, N=D, K=Sk ; B = memT [D][Sk] ; fp32 out
  gemm_f16<1, 0, false><<<dim3(DD / 128, SQL / 128, B_), 256, 0, stream>>>(
      P, memT, nullptr, nullptr, out, DD, SKL,
      (long)SQL * SKL, (long)DD * SKL, (long)SQL * DD);
}

// Round 17
// 353.902 us; speedup vs baseline: 2.1072x; 1.0511x over previous
//
#include <hip/hip_runtime.h>

// Round 17: T1 XCD-aware chunked swizzle (m204 bijective form) on all three
// GEMMs. R16 diagnosis: QK 124us at 556 TF (vs PV 980) with FETCH 278MB vs
// 66 ideal -- consecutive N-tile blocks sharing an A-panel land on different
// XCD L2s. Swizzle j=(i%8)*(nwg/8)+i/8 gives each XCD a contiguous tile span.
// Everything else identical to R16 (372us, absmax 0.0742).

typedef __attribute__((ext_vector_type(8))) _Float16 f16x8;
typedef __attribute__((ext_vector_type(4))) float f32x4;
typedef unsigned short u16;
typedef unsigned int u32;

#define B_ 8
#define SQL 2048
#define SKL 2048
#define DD 1024
#define NEGC -1000000000.0f

static __device__ __forceinline__ u16 f2h(float x) {
  _Float16 h = (_Float16)x;                       // v_cvt_f16_f32, RNE
  return __builtin_bit_cast(u16, h);
}
static __device__ __forceinline__ float h2f(u16 v) {
  return (float)__builtin_bit_cast(_Float16, v);
}
static __device__ __forceinline__ void gload16(const void* g, void* l) {
  __builtin_amdgcn_global_load_lds((const __attribute__((address_space(1))) u32*)g,
                                   (__attribute__((address_space(3))) u32*)l, 16, 0, 0);
}

// ---------------- convert fp32 -> fp16 (single) ----------------
__global__ __launch_bounds__(256) void cvt16_k(const float* __restrict__ in,
                                               u16* __restrict__ out, long n) {
  long i = ((long)blockIdx.x * 256 + threadIdx.x) * 8;
  long stride = (long)gridDim.x * 256 * 8;
  for (; i < n; i += stride) {
    float4 v0 = *(const float4*)(in + i);
    float4 v1 = *(const float4*)(in + i + 4);
    ushort4 o0 = make_ushort4(f2h(v0.x), f2h(v0.y), f2h(v0.z), f2h(v0.w));
    ushort4 o1 = make_ushort4(f2h(v1.x), f2h(v1.y), f2h(v1.z), f2h(v1.w));
    *(ushort4*)(out + i) = o0;
    *(ushort4*)(out + i + 4) = o1;
  }
}

// ---------------- split fp32 -> fp16 hi + fp16 lo (for W) ----------------
__global__ __launch_bounds__(256) void split16_k(const float* __restrict__ in,
                                                 u16* __restrict__ hi, u16* __restrict__ lo,
                                                 long n) {
  long i = ((long)blockIdx.x * 256 + threadIdx.x) * 4;
  long stride = (long)gridDim.x * 256 * 4;
  for (; i < n; i += stride) {
    float4 v = *(const float4*)(in + i);
    u16 h0 = f2h(v.x), h1 = f2h(v.y), h2 = f2h(v.z), h3 = f2h(v.w);
    *(ushort4*)(hi + i) = make_ushort4(h0, h1, h2, h3);
    *(ushort4*)(lo + i) = make_ushort4(f2h(v.x - h2f(h0)), f2h(v.y - h2f(h1)),
                                       f2h(v.z - h2f(h2)), f2h(v.w - h2f(h3)));
  }
}

// ---------------- fused mem: fp32 [Sk][D] -> memh fp16 + memT fp16 [D][Sk] ----------------
__global__ __launch_bounds__(256) void split_mem16_k(const float* __restrict__ in,
                                                     u16* __restrict__ hi,
                                                     u16* __restrict__ trn) {
  __shared__ u16 t[64][65];
  long bo = (long)blockIdx.z * SKL * DD;
  int r0 = blockIdx.y * 64, c0 = blockIdx.x * 64;
  int tr = threadIdx.x / 16, tc4 = (threadIdx.x % 16) * 4;
#pragma unroll
  for (int i = 0; i < 4; ++i) {
    int r = tr + i * 16;
    long idx = bo + (long)(r0 + r) * DD + c0 + tc4;
    float4 v = *(const float4*)(in + idx);
    u16 h0 = f2h(v.x), h1 = f2h(v.y), h2 = f2h(v.z), h3 = f2h(v.w);
    *(ushort4*)(hi + idx) = make_ushort4(h0, h1, h2, h3);
    t[r][tc4 + 0] = h0; t[r][tc4 + 1] = h1; t[r][tc4 + 2] = h2; t[r][tc4 + 3] = h3;
  }
  __syncthreads();
#pragma unroll
  for (int i = 0; i < 4; ++i) {
    int c = tr + i * 16;   // output row = original column c0+c
    ushort4 v = make_ushort4(t[tc4 + 0][c], t[tc4 + 1][c], t[tc4 + 2][c], t[tc4 + 3][c]);
    *(ushort4*)(trn + bo + (long)(c0 + c) * SKL + r0 + tc4) = v;
  }
}

// ---------------- unified B^T-layout fp16 MFMA GEMM ----------------
// C[m][n] = sum_k A[m][k]*B[n][k]; 128x128 tile, 4 waves (2x2), BK=64,
// mfma_f32_16x16x32_f16, single-buffer LDS, XOR-swizzled via pre-swizzled
// global source. XCD-chunked tile swizzle (T1): each XCD owns a contiguous
// row-major tile span -> A-panel fetched once per XCD.
// TERMS=2: B dual (Bh|Bl), 16-chunk 256B rows.  proj
// TERMS=1: B single, 8-chunk rows.              QK/PV
// OUTMODE: 0 = fp32 ; 1 = fp16 single
template <int TERMS, int OUTMODE, bool BIAS>
__global__ __launch_bounds__(256, 2) void gemm_f16(
    const u16* __restrict__ Ah,
    const u16* __restrict__ Bh, const u16* __restrict__ Bl,
    const float* __restrict__ bias,
    void* __restrict__ C0,
    int N, int K, long batchA, long batchB, long batchC) {
  constexpr int RWB = (TERMS == 2) ? 128 : 64;   // u16 per B LDS row
  __shared__ u16 lA[128 * 64];
  __shared__ u16 lB[128 * RWB];

  // ---- T1 XCD swizzle (bijective; nwg % 8 == 0 in all uses) ----
  const int nx = gridDim.x;
  int i0 = blockIdx.y * nx + blockIdx.x;
  int nwg = nx * gridDim.y;
  int j = (i0 & 7) * (nwg >> 3) + (i0 >> 3);
  const int bx = j % nx, by = j / nx;

  const int bz = blockIdx.z;
  const u16* pAh = Ah + (long)bz * batchA;
  const u16* pBh = Bh + (long)bz * batchB;
  const u16* pBl = (TERMS == 2) ? Bl : nullptr;   // proj W has no batch

  const int tid = threadIdx.x;
  const int l = tid & 63, w = tid >> 6;
  const int wr = w >> 1, wc = w & 1;
  const long am0 = (long)by * 128;
  const long bn0 = (long)bx * 128;

  f32x4 acc[4][4];
#pragma unroll
  for (int i = 0; i < 4; ++i)
#pragma unroll
    for (int j2 = 0; j2 < 4; ++j2) {
      f32x4 z = {0.f, 0.f, 0.f, 0.f};
      acc[i][j2] = z;
    }

  const int lrow = l & 15, lch = l >> 4;

  for (int k0 = 0; k0 < K; k0 += 64) {
    __syncthreads();
    // ---- A stage: single fp16, 8 chunks/row (proven involution) ----
#pragma unroll
    for (int i = 0; i < 4; ++i) {
      int row = i * 32 + (tid >> 3);
      int cc = (tid & 7) ^ (row & 7);
      gload16(pAh + (am0 + row) * K + k0 + cc * 8, &lA[row * 64 + (tid & 7) * 8]);
    }
    // ---- B stage ----
    if (TERMS == 2) {
#pragma unroll
      for (int i = 0; i < 8; ++i) {
        int row = i * 16 + (tid >> 4);
        int s = tid & 15;
        int cc = s ^ (row & 15);
        const u16* src = (cc < 8) ? (pBh + (bn0 + row) * K + k0 + cc * 8)
                                  : (pBl + (bn0 + row) * K + k0 + (cc - 8) * 8);
        gload16(src, &lB[row * 128 + s * 8]);
      }
    } else {
#pragma unroll
      for (int i = 0; i < 4; ++i) {
        int row = i * 32 + (tid >> 3);
        int cc = (tid & 7) ^ (row & 7);
        gload16(pBh + (bn0 + row) * K + k0 + cc * 8, &lB[row * 64 + (tid & 7) * 8]);
      }
    }
    __syncthreads();

#pragma unroll
    for (int kk = 0; kk < 2; ++kk) {
      if (TERMS == 2) {
        f16x8 ah[4], bh[4], bl_[4];
#pragma unroll
        for (int f = 0; f < 4; ++f) {
          int ra = wr * 64 + f * 16 + lrow;
          int rb = wc * 64 + f * 16 + lrow;
          int c = kk * 4 + lch;
          ah[f] = *(const f16x8*)&lA[ra * 64 + (c ^ (ra & 7)) * 8];
          bh[f] = *(const f16x8*)&lB[rb * 128 + (c ^ (rb & 15)) * 8];
          bl_[f] = *(const f16x8*)&lB[rb * 128 + ((8 + c) ^ (rb & 15)) * 8];
        }
#pragma unroll
        for (int mf = 0; mf < 4; ++mf)
#pragma unroll
          for (int nf = 0; nf < 4; ++nf) {
            acc[mf][nf] = __builtin_amdgcn_mfma_f32_16x16x32_f16(ah[mf], bh[nf], acc[mf][nf], 0, 0, 0);
            acc[mf][nf] = __builtin_amdgcn_mfma_f32_16x16x32_f16(ah[mf], bl_[nf], acc[mf][nf], 0, 0, 0);
          }
      } else {
        f16x8 ah[4], bh[4];
#pragma unroll
        for (int f = 0; f < 4; ++f) {
          int ra = wr * 64 + f * 16 + lrow;
          int rb = wc * 64 + f * 16 + lrow;
          int c = kk * 4 + lch;
          ah[f] = *(const f16x8*)&lA[ra * 64 + (c ^ (ra & 7)) * 8];
          bh[f] = *(const f16x8*)&lB[rb * 64 + (c ^ (rb & 7)) * 8];
        }
#pragma unroll
        for (int mf = 0; mf < 4; ++mf)
#pragma unroll
          for (int nf = 0; nf < 4; ++nf)
            acc[mf][nf] = __builtin_amdgcn_mfma_f32_16x16x32_f16(ah[mf], bh[nf], acc[mf][nf], 0, 0, 0);
      }
    }
  }

  // epilogue: C/D layout col = lane&15, row = (lane>>4)*4 + reg
#pragma unroll
  for (int mf = 0; mf < 4; ++mf)
#pragma unroll
    for (int nf = 0; nf < 4; ++nf)
#pragma unroll
      for (int r = 0; r < 4; ++r) {
        long row = am0 + wr * 64 + mf * 16 + (l >> 4) * 4 + r;
        long col = bn0 + wc * 64 + nf * 16 + (l & 15);
        float v = acc[mf][nf][r];
        if (BIAS) v += bias[col];
        long idx = (long)bz * batchC + row * N + col;
        if (OUTMODE == 0) ((float*)C0)[idx] = v;
        else              ((u16*)C0)[idx] = f2h(v);
      }
}

// ---------------- mask + row softmax: S fp32, mask int32 -> P fp16 ----------------
__global__ __launch_bounds__(256) void softmax16_k(const float* __restrict__ S,
                                                   const int* __restrict__ M,
                                                   u16* __restrict__ P) {
  long row = blockIdx.x;
  const float* s = S + row * SKL;
  const int* m = M + row * SKL;
  u16* p = P + row * SKL;
  int t = threadIdx.x;
  float x[8];
#pragma unroll
  for (int j = 0; j < 2; ++j) {
    float4 v = *(const float4*)(s + t * 8 + j * 4);
    int4 q = *(const int4*)(m + t * 8 + j * 4);
    x[j * 4 + 0] = q.x ? v.x : v.x + NEGC;
    x[j * 4 + 1] = q.y ? v.y : v.y + NEGC;
    x[j * 4 + 2] = q.z ? v.z : v.z + NEGC;
    x[j * 4 + 3] = q.w ? v.w : v.w + NEGC;
  }
  float mx = x[0];
#pragma unroll
  for (int j = 1; j < 8; ++j) mx = fmaxf(mx, x[j]);
#pragma unroll
  for (int o = 32; o >= 1; o >>= 1) mx = fmaxf(mx, __shfl_xor(mx, o, 64));
  __shared__ float red[8];
  if ((t & 63) == 0) red[t >> 6] = mx;
  __syncthreads();
  mx = fmaxf(fmaxf(red[0], red[1]), fmaxf(red[2], red[3]));
  float e[8], sum = 0.f;
#pragma unroll
  for (int j = 0; j < 8; ++j) { e[j] = __expf(x[j] - mx); sum += e[j]; }
#pragma unroll
  for (int o = 32; o >= 1; o >>= 1) sum += __shfl_xor(sum, o, 64);
  if ((t & 63) == 0) red[4 + (t >> 6)] = sum;
  __syncthreads();
  float inv = 1.f / (red[4] + red[5] + red[6] + red[7]);
  ushort4 o0 = make_ushort4(f2h(e[0] * inv), f2h(e[1] * inv), f2h(e[2] * inv), f2h(e[3] * inv));
  ushort4 o1 = make_ushort4(f2h(e[4] * inv), f2h(e[5] * inv), f2h(e[6] * inv), f2h(e[7] * inv));
  *(ushort4*)(p + t * 8) = o0;
  *(ushort4*)(p + t * 8 + 4) = o1;
}

extern "C" void kernel_launch(void* const* d_in, const int* in_sizes, int n_in,
                              void* d_out, int out_size, void* d_ws, size_t ws_size,
                              hipStream_t stream) {
  const float* query = (const float*)d_in[0];
  const float* mem = (const float*)d_in[1];
  const int* mask = (const int*)d_in[2];
  const float* Wm = (const float*)d_in[3];
  const float* bias = (const float*)d_in[4];
  float* out = (float*)d_out;   // fp32 output

  const long nQ = (long)B_ * SQL * DD;   // 16.7M
  const long nW = (long)DD * DD;
  const long nS = (long)B_ * SQL * SKL;

  char* ws = (char*)d_ws;
  u16* q16 = (u16*)ws; ws += nQ * 2;    // fp16(query); becomes P after proj+QK
  u16* memh = (u16*)ws; ws += nQ * 2;
  u16* memT = (u16*)ws; ws += nQ * 2;
  u16* q1 = (u16*)ws; ws += nQ * 2;     // projected q, fp16
  u16* wh = (u16*)ws; ws += nW * 2;
  u16* wl = (u16*)ws; ws += nW * 2;
  float* S = (float*)ws; ws += nS * 4;
  u16* P = q16;   // q16 dead after projection

  cvt16_k<<<2048, 256, 0, stream>>>(query, q16, nQ);
  split16_k<<<512, 256, 0, stream>>>(Wm, wh, wl, nW);
  split_mem16_k<<<dim3(DD / 64, SKL / 64, B_), 256, 0, stream>>>(mem, memh, memT);

  // projection (2-term): M=16384, N=D, K=D ; q -> fp16
  gemm_f16<2, 1, true><<<dim3(DD / 128, (B_ * SQL) / 128, 1), 256, 0, stream>>>(
      q16, wh, wl, bias, q1, DD, DD, 0, 0, 0);
  // logits (1-term): per batch M=Sq, N=Sk, K=D ; fp32 S
  gemm_f16<1, 0, false><<<dim3(SKL / 128, SQL / 128, B_), 256, 0, stream>>>(
      q1, memh, nullptr, nullptr, S, SKL, DD,
      (long)SQL * DD, (long)SKL * DD, (long)SQL * SKL);
  // mask + softmax -> P fp16
  softmax16_k<<<B_ * SQL, 256, 0, stream>>>(S, mask, P);
  // PV (1-term): per batch M=Sq, N=D, K=Sk ; B = memT [D][Sk] ; fp32 out
  gemm_f16<1, 0, false><<<dim3(DD / 128, SQL / 128, B_), 256, 0, stream>>>(
      P, memT, nullptr, nullptr, out, DD, SKL,
      (long)SQL * SKL, (long)DD * SKL, (long)SQL * DD);
}